// Round 2
// baseline (356.224 us; speedup 1.0000x reference)
//
#include <hip/hip_runtime.h>
#include <hip/hip_bf16.h>

// HopfieldTSP: reference iterates x = sign(w @ x) 1000 times, with
// w = -adj off-diagonal, w_ii = 2*rowsum_i.
//
// Math: for any x in {±1}^n, (w@x)_i = (2*rowsum_i + adj_ii)*x_i - (adj@x)_i,
// and since adj >= 0, |(adj@x)_i| <= rowsum_i < 2*rowsum_i. So every ±1
// vector is a fixed point: sign(w@x) = x. Hence x_1000 = x_1 = sign(w @ x0).
// The entire problem is ONE fused matvec + rowsum pass (268 MB HBM read,
// ~43 us floor at 6.3 TB/s).
//
// R2: stage x in LDS once per block (kills the 256 MiB of redundant global
// x re-reads and halves VMEM instructions in the hot loop). 512-thread
// blocks = 8 rows/block: 4 blocks/CU (wave-capped), LDS 128 KiB/CU.

#define N_CITIES 8192
#define NV4 (N_CITIES / 4)          // 2048 float4 per row
#define ROWS_PER_BLOCK 8
#define BLOCK (64 * ROWS_PER_BLOCK) // 512 threads

__global__ __launch_bounds__(BLOCK) void
hopfield_onestep_kernel(const float* __restrict__ adj,
                        const float* __restrict__ x,
                        float* __restrict__ out) {
    __shared__ float4 xs[NV4];      // full x vector, 32 KB

    // Cooperative stage of x into LDS: 4 coalesced float4 loads/thread.
    const float4* __restrict__ xg = (const float4*)x;
    #pragma unroll
    for (int c = threadIdx.x; c < NV4; c += BLOCK)
        xs[c] = xg[c];
    __syncthreads();

    const int wave = threadIdx.x >> 6;
    const int lane = threadIdx.x & 63;
    const int row  = blockIdx.x * ROWS_PER_BLOCK + wave;  // grid exact, no guard

    const float4* __restrict__ arow =
        (const float4*)(adj + (size_t)row * N_CITIES);

    float dot  = 0.0f;   // sum_j adj[row][j] * x[j]
    float rsum = 0.0f;   // sum_j adj[row][j]

    // 2048 float4 / 64 lanes = 32 iterations; unroll 4 -> 4 a-loads in
    // flight per wave (64 KB/CU at 32 waves/CU: latency amply hidden)
    // without blowing the VGPR budget past the 8-waves/EU cliff.
    #pragma unroll 4
    for (int c = lane; c < NV4; c += 64) {
        float4 a  = arow[c];     // HBM stream (mandatory traffic)
        float4 xv = xs[c];       // LDS, 2-way bank aliasing = free
        dot  += a.x * xv.x + a.y * xv.y + a.z * xv.z + a.w * xv.w;
        rsum += a.x + a.y + a.z + a.w;
    }

    // wave64 reduction
    #pragma unroll
    for (int off = 32; off > 0; off >>= 1) {
        dot  += __shfl_down(dot,  off, 64);
        rsum += __shfl_down(rsum, off, 64);
    }

    if (lane == 0) {
        const float* xsf = (const float*)xs;
        float xi  = xsf[row & (N_CITIES - 1)];
        float aii = adj[(size_t)row * N_CITIES + row];
        float y   = (aii + 2.0f * rsum) * xi - dot;
        out[row]  = (y > 0.0f) ? 1.0f : ((y < 0.0f) ? -1.0f : 0.0f);
    }
}

extern "C" void kernel_launch(void* const* d_in, const int* in_sizes, int n_in,
                              void* d_out, int out_size, void* d_ws, size_t ws_size,
                              hipStream_t stream) {
    const float* adj = (const float*)d_in[0];
    const float* x   = (const float*)d_in[1];
    float* out       = (float*)d_out;

    const int grid = N_CITIES / ROWS_PER_BLOCK;  // 1024 blocks
    hopfield_onestep_kernel<<<grid, BLOCK, 0, stream>>>(adj, x, out);
}